// Round 4
// baseline (51976.245 us; speedup 1.0000x reference)
//
#include <hip/hip_runtime.h>
#include <math.h>

#define DEV_INLINE __device__ __forceinline__

static constexpr int Bn = 64;     // batch
static constexpr int Tn = 512;    // time
static constexpr int En = 512;    // embed
static constexpr int Hn = 1024;   // hidden
static constexpr int Cn = 256;    // classes
static constexpr int Gn = 4 * Hn; // 4096 gates

typedef float v4f __attribute__((ext_vector_type(4)));

DEV_INLINE float sigmoidf_(float v) { return 1.f / (1.f + __expf(-v)); }

// ---------------------------------------------------------------------------
// Generic fp32 tiled GEMM:  C[M,N] = A[M,K] * B[N,K]^T + bias1[n] (+bias2[n])
// ---------------------------------------------------------------------------
__global__ __launch_bounds__(256) void gemm_tt(
    const float* __restrict__ A, const float* __restrict__ Bm,
    const float* __restrict__ bias1, const float* __restrict__ bias2,
    float* __restrict__ Cm, int M, int N, int K)
{
  constexpr int KC = 32;
  __shared__ float As[KC][68];
  __shared__ float Bs[KC][68];
  const int tid = threadIdx.x;
  const int tx = tid & 15, ty = tid >> 4;
  const int m0 = blockIdx.x * 64, n0 = blockIdx.y * 64;

  float acc[4][4] = {};

  for (int k0 = 0; k0 < K; k0 += KC) {
    __syncthreads();
    #pragma unroll
    for (int j = 0; j < 2; ++j) {
      int f = tid + j * 256;
      int row = f >> 3;
      int c4 = f & 7;
      float4 va = *reinterpret_cast<const float4*>(&A[(size_t)(m0 + row) * K + k0 + c4 * 4]);
      As[c4 * 4 + 0][row] = va.x; As[c4 * 4 + 1][row] = va.y;
      As[c4 * 4 + 2][row] = va.z; As[c4 * 4 + 3][row] = va.w;
      float4 vb = *reinterpret_cast<const float4*>(&Bm[(size_t)(n0 + row) * K + k0 + c4 * 4]);
      Bs[c4 * 4 + 0][row] = vb.x; Bs[c4 * 4 + 1][row] = vb.y;
      Bs[c4 * 4 + 2][row] = vb.z; Bs[c4 * 4 + 3][row] = vb.w;
    }
    __syncthreads();
    #pragma unroll
    for (int k = 0; k < KC; ++k) {
      float4 a4 = *reinterpret_cast<const float4*>(&As[k][ty * 4]);
      float4 b4 = *reinterpret_cast<const float4*>(&Bs[k][tx * 4]);
      float ar[4] = {a4.x, a4.y, a4.z, a4.w};
      float br[4] = {b4.x, b4.y, b4.z, b4.w};
      #pragma unroll
      for (int i = 0; i < 4; ++i)
        #pragma unroll
        for (int j = 0; j < 4; ++j)
          acc[i][j] += ar[i] * br[j];
    }
  }

  #pragma unroll
  for (int j = 0; j < 4; ++j) {
    int n = n0 + tx * 4 + j;
    float bb = bias1[n];
    if (bias2) bb += bias2[n];
    #pragma unroll
    for (int i = 0; i < 4; ++i)
      Cm[(size_t)(m0 + ty * 4 + i) * N + n] = acc[i][j] + bb;
  }
}

// ---------------------------------------------------------------------------
// W-stationary persistent LSTM. 256 blocks x 512 threads (1 block/CU).
// Block (bg 0..3, hg 0..63): batch rows [bg*16,+16), h-cols [hg*16,+16).
// bg = (bid&7)>>1 so each XCD (bid%8 round-robin) hosts ONE batch group ->
// its L2 needs only that group's 64KB h slice per step (MSHR-shared).
// W held in registers (wv[4][8] float4 = 128 VGPR) for the whole kernel.
// Per step: agent acquire fence (buffer_inv: drop stale L1/L2) -> NORMAL
// cached staging loads -> LDS, 2048 reg-resident FMAs, reduce-scatter,
// elementwise, write-through h store, tree barrier.
// ---------------------------------------------------------------------------

#define FG_(b,g,j,H) a[(g)*16+(b)] = __builtin_fmaf((H).w, wv[g][j].w, \
    __builtin_fmaf((H).z, wv[g][j].z, __builtin_fmaf((H).y, wv[g][j].y, \
    __builtin_fmaf((H).x, wv[g][j].x, a[(g)*16+(b)]))));
#define JS_(b,j) { v4f Hv = hsm4[(b)*256 + jidx[j]]; \
  FG_(b,0,j,Hv) FG_(b,1,j,Hv) FG_(b,2,j,Hv) FG_(b,3,j,Hv) }
#define ROW_(b) JS_(b,0) JS_(b,1) JS_(b,2) JS_(b,3) JS_(b,4) JS_(b,5) JS_(b,6) JS_(b,7)
#define KLOOP ROW_(0) ROW_(1) ROW_(2) ROW_(3) ROW_(4) ROW_(5) ROW_(6) ROW_(7) \
              ROW_(8) ROW_(9) ROW_(10) ROW_(11) ROW_(12) ROW_(13) ROW_(14) ROW_(15)

#define RROUND(L, MASK, BIT) \
  _Pragma("unroll") \
  for (int j2 = 0; j2 < (L); ++j2) { \
    float snd = (BIT) ? a[j2] : a[j2 + (L)]; \
    float kp  = (BIT) ? a[j2 + (L)] : a[j2]; \
    a[j2] = kp + __shfl_xor(snd, (MASK)); \
  }

__global__ __launch_bounds__(512, 2) void lstm_persistent(
    const int* __restrict__ x,        // [B, T]
    const float* __restrict__ Whh,    // [4H, H]
    const float* __restrict__ proj,   // [C, 4H] class gates incl. both biases
    float* __restrict__ hs,           // [B, T, H]
    int* __restrict__ flags)          // tree barrier state
{
  __shared__ __align__(16) float hsm[16 * 1024];   // 64 KB staged h tile
  float* gbufF  = hsm;          // gate exchange buffer aliases rows 0..1023
  float* hstage = hsm + 1024;   // h repack buffer

  const int tid = threadIdx.x;
  const int bid = blockIdx.x;
  const int bg = (bid & 7) >> 1;              // one bg per XCD (round-robin)
  const int hg = ((bid >> 3) << 1) | (bid & 1); // 0..63, bijective with bg
  const int b0 = bg * 16;

  const int w_ = tid >> 6;       // wave 0..7
  const int lane = tid & 63;
  const int hcm = lane & 1;
  const int ks = lane >> 1;      // 0..31 K-split
  const int hc_l = w_ * 2 + hcm; // 0..15
  const int hc = hg * 16 + hc_l;

  // ---- one-time W preload into registers (read order rotated by ks)
  v4f wv[4][8];
  #pragma unroll
  for (int g = 0; g < 4; ++g) {
    const float* wb = Whh + ((size_t)(g * 1024 + hc)) * 1024 + ks * 32;
    #pragma unroll
    for (int j = 0; j < 8; ++j)
      wv[g][j] = *(const v4f*)(wb + ((ks + j) & 7) * 4);
  }
  int jidx[8];
  #pragma unroll
  for (int j = 0; j < 8; ++j) jidx[j] = ks * 8 + ((ks + j) & 7);

  v4f* hsm4 = (v4f*)hsm;

  const int ew = (tid < 256);
  const int b_l = tid >> 4, hcl = tid & 15;        // elementwise mapping
  const int* xp = x + (size_t)(b0 + b_l) * Tn;
  float cst = 0.f;

  // ---- tree barrier pointers (per group: 8 L0 + 1 L1 + 1 GEN, 128B lines)
  int* L0  = flags + (size_t)(bg * 10 + (hg >> 3)) * 32;
  int* L1  = flags + (size_t)(bg * 10 + 8) * 32;
  int* GEN = flags + (size_t)(bg * 10 + 9) * 32;

  // final element ids after reduce-scatter (bit-reversed ks)
  const int e0 = ((ks & 1) << 5) | (((ks >> 1) & 1) << 4) | (((ks >> 2) & 1) << 3)
               | (((ks >> 3) & 1) << 2) | (((ks >> 4) & 1) << 1);
  const int e1 = e0 | 1;

  const int c4 = tid & 255;      // staging column (float4 granularity)
  const int rb = tid >> 8;       // staging row base 0/1

  for (int t = 0; t < Tn; ++t) {
    if (t > 0) {
      // make remote write-through h[t-1] visible: drop clean L1/L2 lines
      __builtin_amdgcn_fence(__ATOMIC_ACQUIRE, "agent");
    }

    // class projection prefetch (read-only data: cache-safe, long slack)
    float p0 = 0.f, p1 = 0.f, p2 = 0.f, p3 = 0.f;
    if (ew) {
      int cls = xp[t];
      const float* pb = proj + (size_t)cls * Gn + hg * 16 + hcl;
      p0 = pb[0]; p1 = pb[Hn]; p2 = pb[2 * Hn]; p3 = pb[3 * Hn];
    }

    if (t > 0) {
      // stage h[t-1]: NORMAL cached 16B loads (post-inv => coherent),
      // L2 MSHRs merge the 32 same-XCD blocks' identical requests.
      v4f r[8];
      #pragma unroll
      for (int l = 0; l < 8; ++l)
        r[l] = *(const v4f*)(hs + ((size_t)(b0 + rb + 2 * l) * Tn + (t - 1)) * Hn + c4 * 4);
      #pragma unroll
      for (int l = 0; l < 8; ++l)
        hsm4[tid + l * 512] = r[l];
    }
    __syncthreads();

    float a[64];
    #pragma unroll
    for (int i = 0; i < 64; ++i) a[i] = 0.f;

    if (t > 0) { KLOOP }

    // reduce-scatter over the 32 ks lanes: 62 shuffles total
    RROUND(32, 2, (ks & 1))
    RROUND(16, 4, ((ks >> 1) & 1))
    RROUND(8, 8, ((ks >> 2) & 1))
    RROUND(4, 16, ((ks >> 3) & 1))
    RROUND(2, 32, ((ks >> 4) & 1))

    __syncthreads();   // hsm KLOOP reads done before gbuf (aliased) writes
    gbufF[(e0 & 15) * 64 + (e0 >> 4) * 16 + hc_l] = a[0];
    gbufF[(e1 & 15) * 64 + (e1 >> 4) * 16 + hc_l] = a[1];
    __syncthreads();

    if (ew) {
      float g0 = gbufF[b_l * 64 +  0 + hcl] + p0;
      float g1 = gbufF[b_l * 64 + 16 + hcl] + p1;
      float g2 = gbufF[b_l * 64 + 32 + hcl] + p2;
      float g3 = gbufF[b_l * 64 + 48 + hcl] + p3;
      float ig = sigmoidf_(g0), fg = sigmoidf_(g1);
      float gg = tanhf(g2),     og = sigmoidf_(g3);
      cst = fg * cst + ig * gg;
      hstage[tid] = og * tanhf(cst);
    }
    __syncthreads();

    if (tid < 64) {
      // write-through 16B stores: fabric holds fresh h for all XCDs
      float* sp = hs + ((size_t)(b0 + (tid >> 2)) * Tn + t) * Hn
                     + hg * 16 + (tid & 3) * 4;
      v4f v = *(const v4f*)&hstage[tid * 4];
      asm volatile(
        "global_store_dwordx4 %0, %1, off sc0 sc1\n\t"
        "s_waitcnt vmcnt(0)"
        :: "v"(sp), "v"(v) : "memory");
    }

    if (t + 1 < Tn) {
      __syncthreads();   // all h stores drained before arrival
      if (tid == 0) {
        int target = 8 * (t + 1);
        int old = __hip_atomic_fetch_add(L0, 1, __ATOMIC_RELAXED,
                                         __HIP_MEMORY_SCOPE_AGENT);
        if (old == target - 1) {
          int o1 = __hip_atomic_fetch_add(L1, 1, __ATOMIC_RELAXED,
                                          __HIP_MEMORY_SCOPE_AGENT);
          if (o1 == target - 1)
            __hip_atomic_store(GEN, t + 1, __ATOMIC_RELAXED,
                               __HIP_MEMORY_SCOPE_AGENT);
        }
        while (__hip_atomic_load(GEN, __ATOMIC_RELAXED,
                                 __HIP_MEMORY_SCOPE_AGENT) < t + 1)
          __builtin_amdgcn_s_sleep(8);
      }
      __syncthreads();
    }
  }
}

// ---------------------------------------------------------------------------
extern "C" void kernel_launch(void* const* d_in, const int* in_sizes, int n_in,
                              void* d_out, int out_size, void* d_ws, size_t ws_size,
                              hipStream_t stream) {
  const int*   x     = (const int*)  d_in[0];
  const float* embed = (const float*)d_in[1];
  const float* Wih   = (const float*)d_in[2];
  const float* Whh   = (const float*)d_in[3];
  const float* bih   = (const float*)d_in[4];
  const float* bhh   = (const float*)d_in[5];
  const float* fcW   = (const float*)d_in[6];
  const float* fcb   = (const float*)d_in[7];
  float* out = (float*)d_out;

  char* ws = (char*)d_ws;
  const size_t flagBytes = 32768;
  const size_t projBytes = (size_t)Cn * Gn * sizeof(float);          // 4 MB
  const size_t hsBytes   = (size_t)Bn * Tn * Hn * sizeof(float);     // 128 MB
  const size_t need = flagBytes + projBytes + hsBytes;
  if (ws_size < need) {
    hipMemsetAsync(d_out, 0, (size_t)out_size * sizeof(float), stream);
    return;
  }
  float* proj = (float*)(ws + flagBytes);
  float* hs   = (float*)(ws + flagBytes + projBytes);

  // zero barrier flags every call (graph-capture-safe async memset)
  hipMemsetAsync(d_ws, 0, flagBytes, stream);

  // 1) proj[cls, 4H] = embed[cls,:] @ W_ih^T + b_ih + b_hh
  dim3 g1(Cn / 64, Gn / 64);   // (4, 64)
  gemm_tt<<<g1, 256, 0, stream>>>(embed, Wih, bih, bhh, proj, Cn, Gn, En);

  // 2) W-stationary persistent recurrence
  lstm_persistent<<<256, 512, 0, stream>>>(x, Whh, proj, hs, (int*)d_ws);

  // 3) out[b*T+t, c] = hs[b,t,:] @ fc_W^T + fc_b
  dim3 g3((Bn * Tn) / 64, Cn / 64);  // (512, 4)
  gemm_tt<<<g3, 256, 0, stream>>>(hs, fcW, fcb, nullptr, out, Bn * Tn, Cn, Hn);
}

// Round 5
// 2302.993 us; speedup vs baseline: 22.5690x; 22.5690x over previous
//
#include <hip/hip_runtime.h>
#include <math.h>

#define DEV_INLINE __device__ __forceinline__

static constexpr int Bn = 64;     // batch
static constexpr int Tn = 512;    // time
static constexpr int En = 512;    // embed
static constexpr int Hn = 1024;   // hidden
static constexpr int Cn = 256;    // classes
static constexpr int Gn = 4 * Hn; // 4096 gates

typedef float v4f __attribute__((ext_vector_type(4)));
typedef _Float16 v8h __attribute__((ext_vector_type(8)));

DEV_INLINE float sigmoidf_(float v) { return 1.f / (1.f + __expf(-v)); }

// ---------------------------------------------------------------------------
// fp32 tiled GEMM:  C[M,N] = A[M,K] * B[N,K]^T + bias1[n] (+bias2[n])
// (used for proj = embed @ W_ih^T + b_ih + b_hh)
// ---------------------------------------------------------------------------
__global__ __launch_bounds__(256) void gemm_tt(
    const float* __restrict__ A, const float* __restrict__ Bm,
    const float* __restrict__ bias1, const float* __restrict__ bias2,
    float* __restrict__ Cm, int M, int N, int K)
{
  constexpr int KC = 32;
  __shared__ float As[KC][68];
  __shared__ float Bs[KC][68];
  const int tid = threadIdx.x;
  const int tx = tid & 15, ty = tid >> 4;
  const int m0 = blockIdx.x * 64, n0 = blockIdx.y * 64;

  float acc[4][4] = {};

  for (int k0 = 0; k0 < K; k0 += KC) {
    __syncthreads();
    #pragma unroll
    for (int j = 0; j < 2; ++j) {
      int f = tid + j * 256;
      int row = f >> 3;
      int c4 = f & 7;
      float4 va = *reinterpret_cast<const float4*>(&A[(size_t)(m0 + row) * K + k0 + c4 * 4]);
      As[c4 * 4 + 0][row] = va.x; As[c4 * 4 + 1][row] = va.y;
      As[c4 * 4 + 2][row] = va.z; As[c4 * 4 + 3][row] = va.w;
      float4 vb = *reinterpret_cast<const float4*>(&Bm[(size_t)(n0 + row) * K + k0 + c4 * 4]);
      Bs[c4 * 4 + 0][row] = vb.x; Bs[c4 * 4 + 1][row] = vb.y;
      Bs[c4 * 4 + 2][row] = vb.z; Bs[c4 * 4 + 3][row] = vb.w;
    }
    __syncthreads();
    #pragma unroll
    for (int k = 0; k < KC; ++k) {
      float4 a4 = *reinterpret_cast<const float4*>(&As[k][ty * 4]);
      float4 b4 = *reinterpret_cast<const float4*>(&Bs[k][tx * 4]);
      float ar[4] = {a4.x, a4.y, a4.z, a4.w};
      float br[4] = {b4.x, b4.y, b4.z, b4.w};
      #pragma unroll
      for (int i = 0; i < 4; ++i)
        #pragma unroll
        for (int j = 0; j < 4; ++j)
          acc[i][j] += ar[i] * br[j];
    }
  }

  #pragma unroll
  for (int j = 0; j < 4; ++j) {
    int n = n0 + tx * 4 + j;
    float bb = bias1[n];
    if (bias2) bb += bias2[n];
    #pragma unroll
    for (int i = 0; i < 4; ++i)
      Cm[(size_t)(m0 + ty * 4 + i) * N + n] = acc[i][j] + bb;
  }
}

// ---------------------------------------------------------------------------
// FC GEMM reading fp16 A (hs16, layout [t][b][h], row index m = t*64+b),
// writing out[b][t][c] fp32.  out = A @ fc_W^T + fc_b.
// ---------------------------------------------------------------------------
__global__ __launch_bounds__(256) void gemm_fc(
    const _Float16* __restrict__ A,   // [32768][1024] fp16
    const float* __restrict__ Bm,     // fc_W [256][1024]
    const float* __restrict__ bias,   // fc_b [256]
    float* __restrict__ out)          // [64][512][256]
{
  constexpr int KC = 32;
  __shared__ float As[KC][68];
  __shared__ float Bs[KC][68];
  const int tid = threadIdx.x;
  const int tx = tid & 15, ty = tid >> 4;
  const int m0 = blockIdx.x * 64, n0 = blockIdx.y * 64;

  float acc[4][4] = {};

  for (int k0 = 0; k0 < Hn; k0 += KC) {
    __syncthreads();
    {
      int row = tid >> 2, c8 = tid & 3;     // 64 rows x 4 chunks of 8 halves
      v8h va = *(const v8h*)(A + (size_t)(m0 + row) * Hn + k0 + c8 * 8);
      #pragma unroll
      for (int e = 0; e < 8; ++e) As[c8 * 8 + e][row] = (float)va[e];
    }
    #pragma unroll
    for (int j = 0; j < 2; ++j) {
      int f = tid + j * 256, row = f >> 3, c4 = f & 7;
      float4 vb = *reinterpret_cast<const float4*>(&Bm[(size_t)(n0 + row) * Hn + k0 + c4 * 4]);
      Bs[c4 * 4 + 0][row] = vb.x; Bs[c4 * 4 + 1][row] = vb.y;
      Bs[c4 * 4 + 2][row] = vb.z; Bs[c4 * 4 + 3][row] = vb.w;
    }
    __syncthreads();
    #pragma unroll
    for (int k = 0; k < KC; ++k) {
      float4 a4 = *reinterpret_cast<const float4*>(&As[k][ty * 4]);
      float4 b4 = *reinterpret_cast<const float4*>(&Bs[k][tx * 4]);
      float ar[4] = {a4.x, a4.y, a4.z, a4.w};
      float br[4] = {b4.x, b4.y, b4.z, b4.w};
      #pragma unroll
      for (int i = 0; i < 4; ++i)
        #pragma unroll
        for (int j = 0; j < 4; ++j)
          acc[i][j] += ar[i] * br[j];
    }
  }

  #pragma unroll
  for (int j = 0; j < 4; ++j) {
    int n = n0 + tx * 4 + j;
    float bb = bias[n];
    #pragma unroll
    for (int i = 0; i < 4; ++i) {
      int m = m0 + ty * 4 + i;
      int b = m & 63, t = m >> 6;
      out[((size_t)b * Tn + t) * Cn + n] = acc[i][j] + bb;
    }
  }
}

// ---------------------------------------------------------------------------
// MFMA W-stationary persistent LSTM. 128 blocks x 512 threads.
// Block (bg 0..3, hg 0..31): batch rows [bg*16,+16), h-cols [hg*32,+32).
// Each wave (8/block): gate g=w&3, hc16-half q=w>>2; W fragment for its
// 16 gate-rows x K=1024 held as 32x v8h fp16 = 128 VGPR, loaded once.
// Per step: stage 32KB fp16 h tile (sc0 sc1 coherent 16B loads) into
// XOR-swizzled LDS, 32 chained mfma_f32_16x16x32_f16 per wave (K summed
// in-wave, no cross-lane reduce), gate exchange via LDS, elementwise on
// all 512 threads (c-state per thread), fp16 h store (sc0 sc1), tree
// barrier (4 L0 x 8 + L1 + GEN per batch group, 1 poller/block).
// ---------------------------------------------------------------------------
__global__ __launch_bounds__(512, 2) void lstm_mfma(
    const int* __restrict__ x,        // [B, T]
    const float* __restrict__ Whh,    // [4H, H] fp32
    const float* __restrict__ proj,   // [C, 4H] incl. both biases
    _Float16* __restrict__ hs16,      // [T, B, H] fp16 exchange + FC input
    int* __restrict__ flags)
{
  __shared__ __align__(16) char smem[45056];
  char*      hT     = smem;                         // 32 KB swizzled h tile
  float*     gbuf   = (float*)(smem + 32768);       // 2560 f32 gate exchange
  _Float16*  hstage = (_Float16*)(smem + 43008);    // 512 fp16 h repack

  const int tid = threadIdx.x;
  const int bid = blockIdx.x;
  const int bg = bid >> 5, hg = bid & 31;
  const int b0 = bg * 16;

  const int w = tid >> 6, l = tid & 63;
  const int q = w >> 2, g = w & 3;
  const int mrow = l & 15;            // A row / B col / W row-in-tile
  const int kseg = l >> 4;            // k-segment 0..3 (8 elems each)

  // ---- one-time W preload: fp32 -> fp16 fragments (128 VGPR)
  v8h wv[32];
  {
    const float* wr = Whh + (size_t)(g * Hn + hg * 32 + q * 16 + mrow) * Hn + kseg * 8;
    #pragma unroll
    for (int kk = 0; kk < 32; ++kk) {
      const float* p = wr + kk * 32;
      float4 f0 = *(const float4*)p, f1 = *(const float4*)(p + 4);
      v8h h8;
      h8[0] = (_Float16)f0.x; h8[1] = (_Float16)f0.y;
      h8[2] = (_Float16)f0.z; h8[3] = (_Float16)f0.w;
      h8[4] = (_Float16)f1.x; h8[5] = (_Float16)f1.y;
      h8[6] = (_Float16)f1.z; h8[7] = (_Float16)f1.w;
      wv[kk] = h8;
    }
  }

  // elementwise mapping: one (batch, hc) per thread
  const int eb = tid >> 5, ehc = tid & 31;
  const int* xp = x + (size_t)(b0 + eb) * Tn;
  float cst = 0.f;

  int* L0  = flags + (size_t)(bg * 6 + (hg >> 3)) * 32;
  int* L1  = flags + (size_t)(bg * 6 + 4) * 32;
  int* GEN = flags + (size_t)(bg * 6 + 5) * 32;

  for (int t = 0; t < Tn; ++t) {
    // class projection prefetch (plain cached; overlaps staging)
    const int cls = xp[t];
    const float* pb = proj + (size_t)cls * Gn + hg * 32 + ehc;
    float p0 = pb[0], p1 = pb[Hn], p2 = pb[2 * Hn], p3 = pb[3 * Hn];

    if (t > 0) {
      // stage h[t-1] (32KB contiguous fp16): 4x 16B coherent loads/thread
      const char* sb = (const char*)(hs16 + ((size_t)(t - 1) * Bn + b0) * Hn);
      const char* a0 = sb + tid * 16;
      const char* a1 = a0 + 8192;
      const char* a2 = a0 + 16384;
      const char* a3 = a0 + 24576;
      v4f r0, r1, r2, r3;
      asm volatile(
        "global_load_dwordx4 %0, %4, off sc0 sc1\n\t"
        "global_load_dwordx4 %1, %5, off sc0 sc1\n\t"
        "global_load_dwordx4 %2, %6, off sc0 sc1\n\t"
        "global_load_dwordx4 %3, %7, off sc0 sc1\n\t"
        "s_waitcnt vmcnt(0)"
        : "=&v"(r0), "=&v"(r1), "=&v"(r2), "=&v"(r3)
        : "v"(a0), "v"(a1), "v"(a2), "v"(a3)
        : "memory");
      v4f rr[4] = {r0, r1, r2, r3};
      #pragma unroll
      for (int i = 0; i < 4; ++i) {
        int fo = tid * 16 + i * 8192;        // flat byte offset in tile
        int row = fo >> 11, kb = fo & 2047;  // [16][2048B] rows
        *(v4f*)(hT + row * 2048 + (kb ^ ((row & 7) << 4))) = rr[i];
      }
    }
    __syncthreads();

    v4f acc = {0.f, 0.f, 0.f, 0.f};
    if (t > 0) {
      #pragma unroll
      for (int kk = 0; kk < 32; ++kk) {
        const int kb = kk * 64 + kseg * 16;
        v8h a8 = *(const v8h*)(hT + mrow * 2048 + (kb ^ ((mrow & 7) << 4)));
        acc = __builtin_amdgcn_mfma_f32_16x16x32_f16(a8, wv[kk], acc, 0, 0, 0);
      }
    }

    // D frag: col = l&15 (= hc within q-half), row = 4*kseg + r (= batch)
    #pragma unroll
    for (int r = 0; r < 4; ++r)
      gbuf[(g * 32 + q * 16 + mrow) * 20 + kseg * 4 + r] = acc[r];
    __syncthreads();

    // elementwise: all 512 threads, one (batch, hc) each
    {
      float g0 = gbuf[(0 * 32 + ehc) * 20 + eb] + p0;
      float g1 = gbuf[(1 * 32 + ehc) * 20 + eb] + p1;
      float g2 = gbuf[(2 * 32 + ehc) * 20 + eb] + p2;
      float g3 = gbuf[(3 * 32 + ehc) * 20 + eb] + p3;
      float ig = sigmoidf_(g0), fg = sigmoidf_(g1);
      float gg = tanhf(g2),     og = sigmoidf_(g3);
      cst = fg * cst + ig * gg;
      hstage[eb * 32 + ehc] = (_Float16)(og * tanhf(cst));
    }
    __syncthreads();

    if (tid < 64) {
      // 16B coherent stores: 4 threads cover one batch row (32 hc fp16)
      const int b = tid >> 2, part = tid & 3;
      v4f v = *(const v4f*)(hstage + b * 32 + part * 8);
      _Float16* dp = hs16 + ((size_t)t * Bn + b0 + b) * Hn + hg * 32 + part * 8;
      asm volatile(
        "global_store_dwordx4 %0, %1, off sc0 sc1\n\t"
        "s_waitcnt vmcnt(0)"
        :: "v"(dp), "v"(v) : "memory");
    }

    if (t + 1 < Tn) {
      __syncthreads();   // h stores drained before arrival
      if (tid == 0) {
        const int t8 = 8 * (t + 1);
        int old = __hip_atomic_fetch_add(L0, 1, __ATOMIC_RELAXED,
                                         __HIP_MEMORY_SCOPE_AGENT);
        if (old == t8 - 1) {
          int o1 = __hip_atomic_fetch_add(L1, 1, __ATOMIC_RELAXED,
                                          __HIP_MEMORY_SCOPE_AGENT);
          if (o1 == 4 * (t + 1) - 1)
            __hip_atomic_store(GEN, t + 1, __ATOMIC_RELAXED,
                               __HIP_MEMORY_SCOPE_AGENT);
        }
        while (__hip_atomic_load(GEN, __ATOMIC_RELAXED,
                                 __HIP_MEMORY_SCOPE_AGENT) < t + 1)
          __builtin_amdgcn_s_sleep(8);
      }
      __syncthreads();
    }
  }
}

// ---------------------------------------------------------------------------
extern "C" void kernel_launch(void* const* d_in, const int* in_sizes, int n_in,
                              void* d_out, int out_size, void* d_ws, size_t ws_size,
                              hipStream_t stream) {
  const int*   x     = (const int*)  d_in[0];
  const float* embed = (const float*)d_in[1];
  const float* Wih   = (const float*)d_in[2];
  const float* Whh   = (const float*)d_in[3];
  const float* bih   = (const float*)d_in[4];
  const float* bhh   = (const float*)d_in[5];
  const float* fcW   = (const float*)d_in[6];
  const float* fcb   = (const float*)d_in[7];
  float* out = (float*)d_out;

  char* ws = (char*)d_ws;
  const size_t flagBytes = 32768;
  const size_t projBytes = (size_t)Cn * Gn * sizeof(float);            // 4 MB
  const size_t hsBytes   = (size_t)Tn * Bn * Hn * sizeof(_Float16);    // 64 MB
  const size_t need = flagBytes + projBytes + hsBytes;
  if (ws_size < need) {
    hipMemsetAsync(d_out, 0, (size_t)out_size * sizeof(float), stream);
    return;
  }
  float*     proj = (float*)(ws + flagBytes);
  _Float16*  hs16 = (_Float16*)(ws + flagBytes + projBytes);

  // zero barrier flags every call (graph-capture-safe async memset)
  hipMemsetAsync(d_ws, 0, flagBytes, stream);

  // 1) proj[cls, 4H] = embed[cls,:] @ W_ih^T + b_ih + b_hh
  dim3 g1(Cn / 64, Gn / 64);   // (4, 64)
  gemm_tt<<<g1, 256, 0, stream>>>(embed, Wih, bih, bhh, proj, Cn, Gn, En);

  // 2) MFMA W-stationary persistent recurrence
  lstm_mfma<<<128, 512, 0, stream>>>(x, Whh, proj, hs16, (int*)d_ws);

  // 3) out[b,t,:] = hs16[t,b,:] @ fc_W^T + fc_b
  dim3 g3((Bn * Tn) / 64, Cn / 64);  // (512, 4)
  gemm_fc<<<g3, 256, 0, stream>>>(hs16, fcW, fcb, out);
}

// Round 7
// 2100.725 us; speedup vs baseline: 24.7421x; 1.0963x over previous
//
#include <hip/hip_runtime.h>
#include <math.h>

#define DEV_INLINE __device__ __forceinline__

static constexpr int Bn = 64;     // batch
static constexpr int Tn = 512;    // time
static constexpr int En = 512;    // embed
static constexpr int Hn = 1024;   // hidden
static constexpr int Cn = 256;    // classes
static constexpr int Gn = 4 * Hn; // 4096 gates

typedef float v4f __attribute__((ext_vector_type(4)));
typedef _Float16 v8h __attribute__((ext_vector_type(8)));

DEV_INLINE float sigmoidf_(float v) { return 1.f / (1.f + __expf(-v)); }

// ---------------------------------------------------------------------------
// fp32 tiled GEMM:  C[M,N] = A[M,K] * B[N,K]^T + bias1[n] (+bias2[n])
// (used for proj = embed @ W_ih^T + b_ih + b_hh)
// ---------------------------------------------------------------------------
__global__ __launch_bounds__(256) void gemm_tt(
    const float* __restrict__ A, const float* __restrict__ Bm,
    const float* __restrict__ bias1, const float* __restrict__ bias2,
    float* __restrict__ Cm, int M, int N, int K)
{
  constexpr int KC = 32;
  __shared__ float As[KC][68];
  __shared__ float Bs[KC][68];
  const int tid = threadIdx.x;
  const int tx = tid & 15, ty = tid >> 4;
  const int m0 = blockIdx.x * 64, n0 = blockIdx.y * 64;

  float acc[4][4] = {};

  for (int k0 = 0; k0 < K; k0 += KC) {
    __syncthreads();
    #pragma unroll
    for (int j = 0; j < 2; ++j) {
      int f = tid + j * 256;
      int row = f >> 3;
      int c4 = f & 7;
      float4 va = *reinterpret_cast<const float4*>(&A[(size_t)(m0 + row) * K + k0 + c4 * 4]);
      As[c4 * 4 + 0][row] = va.x; As[c4 * 4 + 1][row] = va.y;
      As[c4 * 4 + 2][row] = va.z; As[c4 * 4 + 3][row] = va.w;
      float4 vb = *reinterpret_cast<const float4*>(&Bm[(size_t)(n0 + row) * K + k0 + c4 * 4]);
      Bs[c4 * 4 + 0][row] = vb.x; Bs[c4 * 4 + 1][row] = vb.y;
      Bs[c4 * 4 + 2][row] = vb.z; Bs[c4 * 4 + 3][row] = vb.w;
    }
    __syncthreads();
    #pragma unroll
    for (int k = 0; k < KC; ++k) {
      float4 a4 = *reinterpret_cast<const float4*>(&As[k][ty * 4]);
      float4 b4 = *reinterpret_cast<const float4*>(&Bs[k][tx * 4]);
      float ar[4] = {a4.x, a4.y, a4.z, a4.w};
      float br[4] = {b4.x, b4.y, b4.z, b4.w};
      #pragma unroll
      for (int i = 0; i < 4; ++i)
        #pragma unroll
        for (int j = 0; j < 4; ++j)
          acc[i][j] += ar[i] * br[j];
    }
  }

  #pragma unroll
  for (int j = 0; j < 4; ++j) {
    int n = n0 + tx * 4 + j;
    float bb = bias1[n];
    if (bias2) bb += bias2[n];
    #pragma unroll
    for (int i = 0; i < 4; ++i)
      Cm[(size_t)(m0 + ty * 4 + i) * N + n] = acc[i][j] + bb;
  }
}

// ---------------------------------------------------------------------------
// FC GEMM reading fp16 A (hs16, layout [t][b][h], row index m = t*64+b),
// writing out[b][t][c] fp32.  out = A @ fc_W^T + fc_b.
// ---------------------------------------------------------------------------
__global__ __launch_bounds__(256) void gemm_fc(
    const _Float16* __restrict__ A,   // [32768][1024] fp16
    const float* __restrict__ Bm,     // fc_W [256][1024]
    const float* __restrict__ bias,   // fc_b [256]
    float* __restrict__ out)          // [64][512][256]
{
  constexpr int KC = 32;
  __shared__ float As[KC][68];
  __shared__ float Bs[KC][68];
  const int tid = threadIdx.x;
  const int tx = tid & 15, ty = tid >> 4;
  const int m0 = blockIdx.x * 64, n0 = blockIdx.y * 64;

  float acc[4][4] = {};

  for (int k0 = 0; k0 < Hn; k0 += KC) {
    __syncthreads();
    {
      int row = tid >> 2, c8 = tid & 3;     // 64 rows x 4 chunks of 8 halves
      v8h va = *(const v8h*)(A + (size_t)(m0 + row) * Hn + k0 + c8 * 8);
      #pragma unroll
      for (int e = 0; e < 8; ++e) As[c8 * 8 + e][row] = (float)va[e];
    }
    #pragma unroll
    for (int j = 0; j < 2; ++j) {
      int f = tid + j * 256, row = f >> 3, c4 = f & 7;
      float4 vb = *reinterpret_cast<const float4*>(&Bm[(size_t)(n0 + row) * Hn + k0 + c4 * 4]);
      Bs[c4 * 4 + 0][row] = vb.x; Bs[c4 * 4 + 1][row] = vb.y;
      Bs[c4 * 4 + 2][row] = vb.z; Bs[c4 * 4 + 3][row] = vb.w;
    }
    __syncthreads();
    #pragma unroll
    for (int k = 0; k < KC; ++k) {
      float4 a4 = *reinterpret_cast<const float4*>(&As[k][ty * 4]);
      float4 b4 = *reinterpret_cast<const float4*>(&Bs[k][tx * 4]);
      float ar[4] = {a4.x, a4.y, a4.z, a4.w};
      float br[4] = {b4.x, b4.y, b4.z, b4.w};
      #pragma unroll
      for (int i = 0; i < 4; ++i)
        #pragma unroll
        for (int j = 0; j < 4; ++j)
          acc[i][j] += ar[i] * br[j];
    }
  }

  #pragma unroll
  for (int j = 0; j < 4; ++j) {
    int n = n0 + tx * 4 + j;
    float bb = bias[n];
    #pragma unroll
    for (int i = 0; i < 4; ++i) {
      int m = m0 + ty * 4 + i;
      int b = m & 63, t = m >> 6;
      out[((size_t)b * Tn + t) * Cn + n] = acc[i][j] + bb;
    }
  }
}

// ---------------------------------------------------------------------------
// MFMA W-stationary persistent LSTM. 128 blocks x 512 threads.
// Block (bg = bid>>5, hg = bid&31): batch rows [bg*16,+16), h-cols [hg*32,+32).
// Waves (g 0..3, q 0..1); W fp16 fragments (32 x v8h = 128 VGPR) loaded once.
// A-tile LDS layout = MFMA fragment order [kk 32][kseg 4][mrow 16] x 16B:
//   MFMA read  = hT + kk*1024 + 16*lane      (linear, conflict-free)
//   stage write = hT + tid*16 + i*8192       (linear, conflict-free)
//   swizzle lives in the GLOBAL source address instead (m173 pattern).
// gbuf stride 21 (coprime 32): gate exchange without 8-way conflicts.
// Barrier: all-to-all flag line per (t, bg) — each block stores 1 dword
// (after vmcnt-drained h stores, same wave), waiters poll the 128B line
// with sc0 sc1 loads. One fabric RT instead of 3 serialized atomic RTs.
// Per-(t) flag words, memset'd each call: replay/poison/placement safe.
// ---------------------------------------------------------------------------
__global__ __launch_bounds__(512, 2) void lstm_mfma(
    const int* __restrict__ x,        // [B, T]
    const float* __restrict__ Whh,    // [4H, H] fp32
    const float* __restrict__ proj,   // [C, 4H] incl. both biases
    _Float16* __restrict__ hs16,      // [T, B, H] fp16 exchange + FC input
    int* __restrict__ flags)          // [Tn][4][32] dwords (128B per line)
{
  __shared__ __align__(16) char hT[32768];     // A-tile, fragment-linear
  __shared__ float gbuf[128 * 21];             // gate exchange, stride 21
  __shared__ _Float16 hstage[512];             // 16 x 32 fp16 h repack

  const int tid = threadIdx.x;
  const int bid = blockIdx.x;
  const int bg = bid >> 5, hg = bid & 31;
  const int b0 = bg * 16;

  const int w = tid >> 6, l = tid & 63;
  const int q = w >> 2, g = w & 3;
  const int mrow = l & 15;                     // B col in tile / A row
  const int kseg = l >> 4;                     // k-segment 0..3

  // ---- one-time W preload: fp32 -> fp16 fragments (identical to R5)
  v8h wv[32];
  {
    const float* wr = Whh + (size_t)(g * Hn + hg * 32 + q * 16 + mrow) * Hn + kseg * 8;
    #pragma unroll
    for (int kk = 0; kk < 32; ++kk) {
      const float* p = wr + kk * 32;
      float4 f0 = *(const float4*)p, f1 = *(const float4*)(p + 4);
      v8h h8;
      h8[0] = (_Float16)f0.x; h8[1] = (_Float16)f0.y;
      h8[2] = (_Float16)f0.z; h8[3] = (_Float16)f0.w;
      h8[4] = (_Float16)f1.x; h8[5] = (_Float16)f1.y;
      h8[6] = (_Float16)f1.z; h8[7] = (_Float16)f1.w;
      wv[kk] = h8;
    }
  }

  // elementwise mapping: thread owns (batch eb, hcol ehc)
  const int eb = tid >> 5, ehc = tid & 31;
  const int* xp = x + (size_t)(b0 + eb) * Tn;
  float cst = 0.f;

  // staging: dest = hT + tid*16 + i*8192 (linear). Source offset for dest
  // [kk][kseg][mrow]: mrow=tid&15, kseg=(tid>>4)&3, kk=(tid>>6)+i*8
  // -> src byte = mrow*2048 + kk*64 + kseg*16  (i adds 512).
  const int srcoff = (tid & 15) * 2048 + ((tid >> 4) & 3) * 16 + (tid >> 6) * 64;

  for (int t = 0; t < Tn; ++t) {
    const int cls = xp[t];

    if (t > 0) {
      // ---- all-to-all wait: 32 lanes poll the (t-1, bg) flag line
      if (tid < 32) {
        const int* fp = flags + ((size_t)(t - 1) * 4 + bg) * 32 + tid;
        int v;
        do {
          asm volatile(
            "global_load_dword %0, %1, off sc0 sc1\n\t"
            "s_waitcnt vmcnt(0)"
            : "=v"(v) : "v"(fp) : "memory");
        } while (v == 0);
      }
      __syncthreads();

      // ---- stage h[t-1] (32KB): 4x 16B coherent loads, linear LDS dest
      const char* src = (const char*)(hs16 + ((size_t)(t - 1) * Bn + b0) * Hn);
      const char* s0 = src + srcoff;
      v4f r0, r1, r2, r3;
      asm volatile(
        "global_load_dwordx4 %0, %4, off sc0 sc1\n\t"
        "global_load_dwordx4 %1, %5, off sc0 sc1\n\t"
        "global_load_dwordx4 %2, %6, off sc0 sc1\n\t"
        "global_load_dwordx4 %3, %7, off sc0 sc1\n\t"
        "s_waitcnt vmcnt(0)"
        : "=&v"(r0), "=&v"(r1), "=&v"(r2), "=&v"(r3)
        : "v"(s0), "v"(s0 + 512), "v"(s0 + 1024), "v"(s0 + 1536)
        : "memory");
      *(v4f*)(hT + tid * 16 +     0) = r0;
      *(v4f*)(hT + tid * 16 +  8192) = r1;
      *(v4f*)(hT + tid * 16 + 16384) = r2;
      *(v4f*)(hT + tid * 16 + 24576) = r3;
    }
    __syncthreads();

    v4f acc = {0.f, 0.f, 0.f, 0.f};
    if (t > 0) {
      #pragma unroll
      for (int kk = 0; kk < 32; ++kk) {
        v8h a8 = *(const v8h*)(hT + kk * 1024 + l * 16);   // linear read
        acc = __builtin_amdgcn_mfma_f32_16x16x32_f16(a8, wv[kk], acc, 0, 0, 0);
      }
    }

    // D frag: col = l&15 (hc within q-half), row = 4*kseg + r (batch)
    #pragma unroll
    for (int r = 0; r < 4; ++r)
      gbuf[(g * 32 + q * 16 + mrow) * 21 + kseg * 4 + r] = acc[r];
    __syncthreads();

    // elementwise: all 512 threads, one (batch, hc) each
    {
      const float* pb = proj + (size_t)cls * Gn + hg * 32 + ehc;
      float g0 = gbuf[(0 * 32 + ehc) * 21 + eb] + pb[0];
      float g1 = gbuf[(1 * 32 + ehc) * 21 + eb] + pb[Hn];
      float g2 = gbuf[(2 * 32 + ehc) * 21 + eb] + pb[2 * Hn];
      float g3 = gbuf[(3 * 32 + ehc) * 21 + eb] + pb[3 * Hn];
      float ig = sigmoidf_(g0), fg = sigmoidf_(g1);
      float gg = tanhf(g2),     og = sigmoidf_(g3);
      cst = fg * cst + ig * gg;
      hstage[eb * 32 + ehc] = (_Float16)(og * tanhf(cst));
    }
    __syncthreads();

    if (tid < 64) {
      // 16B coherent stores: 4 threads cover one batch row (32 hc fp16).
      // All 64 stores live in wave 0 -> the wave's vmcnt(0) drains them all
      // before lane 0 publishes the flag (per-wave counter ordering).
      const int b = tid >> 2, part = tid & 3;
      v4f v = *(const v4f*)(hstage + b * 32 + part * 8);
      _Float16* dp = hs16 + ((size_t)t * Bn + b0 + b) * Hn + hg * 32 + part * 8;
      asm volatile(
        "global_store_dwordx4 %0, %1, off sc0 sc1\n\t"
        "s_waitcnt vmcnt(0)"
        :: "v"(dp), "v"(v) : "memory");
      if (tid == 0) {
        int one = 1;
        int* fq = flags + ((size_t)t * 4 + bg) * 32 + hg;
        asm volatile(
          "global_store_dword %0, %1, off sc0 sc1\n\t"
          "s_waitcnt vmcnt(0)"
          :: "v"(fq), "v"(one) : "memory");
      }
    }
    // hT reuse at t+1 is ordered by the poll + __syncthreads there.
  }
}

// ---------------------------------------------------------------------------
extern "C" void kernel_launch(void* const* d_in, const int* in_sizes, int n_in,
                              void* d_out, int out_size, void* d_ws, size_t ws_size,
                              hipStream_t stream) {
  const int*   x     = (const int*)  d_in[0];
  const float* embed = (const float*)d_in[1];
  const float* Wih   = (const float*)d_in[2];
  const float* Whh   = (const float*)d_in[3];
  const float* bih   = (const float*)d_in[4];
  const float* bhh   = (const float*)d_in[5];
  const float* fcW   = (const float*)d_in[6];
  const float* fcb   = (const float*)d_in[7];
  float* out = (float*)d_out;

  char* ws = (char*)d_ws;
  const size_t ctlBytes  = (size_t)Tn * 4 * 32 * 4;                    // 256 KB flags
  const size_t projBytes = (size_t)Cn * Gn * sizeof(float);            // 4 MB
  const size_t hsBytes   = (size_t)Tn * Bn * Hn * sizeof(_Float16);    // 64 MB
  const size_t need = ctlBytes + projBytes + hsBytes;
  if (ws_size < need) {
    hipMemsetAsync(d_out, 0, (size_t)out_size * sizeof(float), stream);
    return;
  }
  float*     proj = (float*)(ws + ctlBytes);
  _Float16*  hs16 = (_Float16*)(ws + ctlBytes + projBytes);

  // zero flags every call (graph-capture-safe async memset)
  hipMemsetAsync(d_ws, 0, ctlBytes, stream);

  // 1) proj[cls, 4H] = embed[cls,:] @ W_ih^T + b_ih + b_hh
  dim3 g1(Cn / 64, Gn / 64);   // (4, 64)
  gemm_tt<<<g1, 256, 0, stream>>>(embed, Wih, bih, bhh, proj, Cn, Gn, En);

  // 2) MFMA W-stationary persistent recurrence
  lstm_mfma<<<128, 512, 0, stream>>>(x, Whh, proj, hs16, (int*)d_ws);

  // 3) out[b,t,:] = hs16[t,b,:] @ fc_W^T + fc_b
  dim3 g3((Bn * Tn) / 64, Cn / 64);  // (512, 4)
  gemm_fc<<<g3, 256, 0, stream>>>(hs16, fcW, fcb, out);
}